// Round 1
// baseline (82229.492 us; speedup 1.0000x reference)
//
#include <hip/hip_runtime.h>

// CGLSTMEncoder: BV=294912 independent sequences, T=120, H=32, D_IN=1.
// Thread-per-sequence, fp32 VALU, h/c in registers, fully unrolled matvecs.
// Weights read with wave-uniform compile-time offsets -> scalar loads.
// The reference's output gate `o` (rows 96:128 of W_ih/W_hh) is dead code
// (h_new = cg * tanh(c_new)) and is skipped entirely.

#define NV 9
#define TLEN 120
#define HS 32
#define BATCH_ 32768

__device__ __forceinline__ float fast_exp2(float x) {
#if __has_builtin(__builtin_amdgcn_exp2f)
  return __builtin_amdgcn_exp2f(x);
#else
  return exp2f(x);
#endif
}
__device__ __forceinline__ float fast_rcp(float x) {
#if __has_builtin(__builtin_amdgcn_rcpf)
  return __builtin_amdgcn_rcpf(x);
#else
  return 1.0f / x;
#endif
}
// sigmoid(x) = 1/(1+2^(-x*log2e))
__device__ __forceinline__ float sigf(float x) {
  return fast_rcp(1.0f + fast_exp2(x * -1.44269504088896f));
}
// tanh(x) = sign(x) * (1 - 2/(2^(2|x|*log2e)+1)); NaN-safe for large |x|
// (exp2 -> inf, rcp(inf) -> 0, result -> +/-1).
__device__ __forceinline__ float tanh_fast(float x) {
  float a = __builtin_fabsf(x);
  float e = fast_exp2(a * 2.88539008177793f);
  float r = fmaf(-2.0f, fast_rcp(1.0f + e), 1.0f);
  return __builtin_copysignf(r, x);
}

__global__ __launch_bounds__(256) void cglstm_kernel(
    const float* __restrict__ x,      // [B, NV*TLEN]
    const float* __restrict__ W_ih,   // [128, 1]  rows: i,f,g,o
    const float* __restrict__ W_hh,   // [128, 32]
    const float* __restrict__ b_ih,   // [128]
    const float* __restrict__ b_hh,   // [128]
    const float* __restrict__ cg_w,   // [32, 1]
    const float* __restrict__ cg_u,   // [32, 32]
    const float* __restrict__ cg_b,   // [32]
    float* __restrict__ out)          // [B, NV*HS] == flat [s*HS + j]
{
  const int s = blockIdx.x * 256 + threadIdx.x;   // sequence id = b*NV + v
  const int b = s / NV;
  const int v = s - b * NV;
  const float* xp = x + (size_t)b * (NV * TLEN) + (size_t)v * TLEN;

  float h[HS], c[HS];
#pragma unroll
  for (int j = 0; j < HS; ++j) { h[j] = 0.0f; c[j] = 0.0f; }

#pragma unroll 1
  for (int t = 0; t < TLEN; ++t) {
    const float xt = xp[t];

    // i, f, g gates + cell update, in j-blocks of 8 to bound live VGPRs.
    // All of h[] (previous step) is read-only here, so in-place c update is safe.
#pragma unroll
    for (int jb = 0; jb < HS; jb += 8) {
      float ip[8], fp[8], gp[8];
#pragma unroll
      for (int r = 0; r < 8; ++r) {
        const int j = jb + r;
        ip[r] = fmaf(W_ih[j],      xt, b_ih[j]      + b_hh[j]);
        fp[r] = fmaf(W_ih[32 + j], xt, b_ih[32 + j] + b_hh[32 + j]);
        gp[r] = fmaf(W_ih[64 + j], xt, b_ih[64 + j] + b_hh[64 + j]);
      }
#pragma unroll
      for (int k = 0; k < HS; ++k) {
        const float hk = h[k];
#pragma unroll
        for (int r = 0; r < 8; ++r) {
          const int j = jb + r;
          ip[r] = fmaf(W_hh[j * HS + k],        hk, ip[r]);
          fp[r] = fmaf(W_hh[(32 + j) * HS + k], hk, fp[r]);
          gp[r] = fmaf(W_hh[(64 + j) * HS + k], hk, gp[r]);
        }
      }
#pragma unroll
      for (int r = 0; r < 8; ++r) {
        const int j = jb + r;
        c[j] = fmaf(sigf(fp[r]), c[j], sigf(ip[r]) * tanh_fast(gp[r]));
      }
    }

    // Contextual gate (uses PREVIOUS h), then h update.
    float cgp[HS];
#pragma unroll
    for (int j = 0; j < HS; ++j) cgp[j] = fmaf(cg_w[j], xt, cg_b[j]);
#pragma unroll
    for (int k = 0; k < HS; ++k) {
      const float hk = h[k];
#pragma unroll
      for (int j = 0; j < HS; ++j) cgp[j] = fmaf(cg_u[j * HS + k], hk, cgp[j]);
    }
#pragma unroll
    for (int j = 0; j < HS; ++j) h[j] = sigf(cgp[j]) * tanh_fast(c[j]);
  }

  // out[s*32 + j] is contiguous per thread and across threads.
  float* op = out + (size_t)s * HS;
#pragma unroll
  for (int j = 0; j < HS; j += 4) {
    float4 o4 = make_float4(h[j], h[j + 1], h[j + 2], h[j + 3]);
    *reinterpret_cast<float4*>(op + j) = o4;
  }
}

extern "C" void kernel_launch(void* const* d_in, const int* in_sizes, int n_in,
                              void* d_out, int out_size, void* d_ws, size_t ws_size,
                              hipStream_t stream) {
  const float* x    = (const float*)d_in[0];
  const float* W_ih = (const float*)d_in[1];
  const float* W_hh = (const float*)d_in[2];
  const float* b_ih = (const float*)d_in[3];
  const float* b_hh = (const float*)d_in[4];
  const float* cg_w = (const float*)d_in[5];
  const float* cg_u = (const float*)d_in[6];
  const float* cg_b = (const float*)d_in[7];
  float* out = (float*)d_out;

  const int total = BATCH_ * NV;   // 294912 sequences
  dim3 grid(total / 256), block(256);
  hipLaunchKernelGGL(cglstm_kernel, grid, block, 0, stream,
                     x, W_ih, W_hh, b_ih, b_hh, cg_w, cg_u, cg_b, out);
}

// Round 2
// 4237.404 us; speedup vs baseline: 19.4056x; 19.4056x over previous
//
#include <hip/hip_runtime.h>

// CGLSTMEncoder: 294912 independent sequences, T=120, H=32, D_IN=1.
// 32 threads per sequence; thread j owns gate element j and keeps its weight
// rows (W_hh rows j/32+j/64+j, cg_u row j) in VGPRs for the whole kernel.
// Per step, h is broadcast through a 32-float LDS buffer (1 write + 8 b128
// reads). Block = 64 threads = 1 wave = 2 sequences -> barriers are free and
// all h communication is wave-lockstep. Grid-stride over sequence pairs
// amortizes the one-time weight load. Output gate `o` (rows 96:128) is dead
// code in the reference and skipped.

#define NV 9
#define TLEN 120
#define HS 32
#define BATCH_ 32768
#define NSEQ (BATCH_ * NV)   // 294912
#define NPAIR (NSEQ / 2)     // 147456
#define GRID_ 12288          // 147456/12288 = 12 pairs per block; balances at
                             // both 8 and 12 resident blocks/CU

__device__ __forceinline__ float fast_exp2(float x) { return __builtin_amdgcn_exp2f(x); }
__device__ __forceinline__ float fast_rcp(float x)  { return __builtin_amdgcn_rcpf(x); }
// sigmoid(x) = 1/(1+2^(-x*log2e))
__device__ __forceinline__ float sigf(float x) {
  return fast_rcp(1.0f + fast_exp2(x * -1.44269504088896f));
}
// tanh(x) = sign(x)*(1 - 2/(2^(2|x|*log2e)+1)); NaN-safe for large |x|.
__device__ __forceinline__ float tanh_fast(float x) {
  float a = __builtin_fabsf(x);
  float e = fast_exp2(a * 2.88539008177793f);
  float r = fmaf(-2.0f, fast_rcp(1.0f + e), 1.0f);
  return __builtin_copysignf(r, x);
}

__global__ __launch_bounds__(64) void cglstm_kernel(
    const float* __restrict__ x,      // [B, NV*TLEN]
    const float* __restrict__ W_ih,   // [128, 1] rows i,f,g,o
    const float* __restrict__ W_hh,   // [128, 32]
    const float* __restrict__ b_ih,   // [128]
    const float* __restrict__ b_hh,   // [128]
    const float* __restrict__ cg_w,   // [32, 1]
    const float* __restrict__ cg_u,   // [32, 32]
    const float* __restrict__ cg_b,   // [32]
    float* __restrict__ out)          // flat [s*HS + j]
{
  const int j   = threadIdx.x & 31;   // owned output element
  const int grp = threadIdx.x >> 5;   // which of the 2 sequences in this wave

  __shared__ float xs[2][TLEN];
  __shared__ float hb[2][HS];

  // ---- one-time weight load into registers (persist across grid-stride) ----
  float wi[HS], wf[HS], wg[HS], wu[HS];
#pragma unroll
  for (int k = 0; k < HS; ++k) {
    wi[k] = W_hh[(j)          * HS + k];
    wf[k] = W_hh[(HS + j)     * HS + k];
    wg[k] = W_hh[(2 * HS + j) * HS + k];
    wu[k] = cg_u[j * HS + k];
  }
  const float wxi = W_ih[j], wxf = W_ih[HS + j], wxg = W_ih[2 * HS + j];
  const float wxc = cg_w[j];
  const float bi = b_ih[j]          + b_hh[j];
  const float bf = b_ih[HS + j]     + b_hh[HS + j];
  const float bg = b_ih[2 * HS + j] + b_hh[2 * HS + j];
  const float bc = cg_b[j];

  for (int p = blockIdx.x; p < NPAIR; p += GRID_) {
    const int s = p * 2 + grp;
    const int b = s / NV;
    const int v = s - b * NV;
    const float* xp = x + (size_t)b * (NV * TLEN) + (size_t)v * TLEN;

    // stage this sequence's 120 inputs into LDS (one-time per pair)
    xs[grp][j]      = xp[j];
    xs[grp][j + 32] = xp[j + 32];
    xs[grp][j + 64] = xp[j + 64];
    if (j < TLEN - 96) xs[grp][j + 96] = xp[j + 96];
    hb[grp][j] = 0.0f;
    float c = 0.0f, hn = 0.0f;
    __syncthreads();

#pragma unroll 1
    for (int t = 0; t < TLEN; ++t) {
      const float xt = xs[grp][t];
      float ai = fmaf(wxi, xt, bi);
      float af = fmaf(wxf, xt, bf);
      float ag = fmaf(wxg, xt, bg);
      float ac = fmaf(wxc, xt, bc);
      const float4* h4 = reinterpret_cast<const float4*>(&hb[grp][0]);
#pragma unroll
      for (int kb = 0; kb < 8; ++kb) {
        const float4 hv = h4[kb];
        ai = fmaf(wi[4 * kb + 0], hv.x, ai);
        ai = fmaf(wi[4 * kb + 1], hv.y, ai);
        ai = fmaf(wi[4 * kb + 2], hv.z, ai);
        ai = fmaf(wi[4 * kb + 3], hv.w, ai);
        af = fmaf(wf[4 * kb + 0], hv.x, af);
        af = fmaf(wf[4 * kb + 1], hv.y, af);
        af = fmaf(wf[4 * kb + 2], hv.z, af);
        af = fmaf(wf[4 * kb + 3], hv.w, af);
        ag = fmaf(wg[4 * kb + 0], hv.x, ag);
        ag = fmaf(wg[4 * kb + 1], hv.y, ag);
        ag = fmaf(wg[4 * kb + 2], hv.z, ag);
        ag = fmaf(wg[4 * kb + 3], hv.w, ag);
        ac = fmaf(wu[4 * kb + 0], hv.x, ac);
        ac = fmaf(wu[4 * kb + 1], hv.y, ac);
        ac = fmaf(wu[4 * kb + 2], hv.z, ac);
        ac = fmaf(wu[4 * kb + 3], hv.w, ac);
      }
      c  = fmaf(sigf(af), c, sigf(ai) * tanh_fast(ag));
      hn = sigf(ac) * tanh_fast(c);
      __syncthreads();            // all lanes done reading h(t-1)
      hb[grp][j] = hn;
      __syncthreads();            // h(t) visible before next step's reads
    }

    out[(size_t)s * HS + j] = hn;  // coalesced: wave covers 256 contiguous B
    __syncthreads();               // xs/hb safe to overwrite next pair
  }
}

extern "C" void kernel_launch(void* const* d_in, const int* in_sizes, int n_in,
                              void* d_out, int out_size, void* d_ws, size_t ws_size,
                              hipStream_t stream) {
  const float* x    = (const float*)d_in[0];
  const float* W_ih = (const float*)d_in[1];
  const float* W_hh = (const float*)d_in[2];
  const float* b_ih = (const float*)d_in[3];
  const float* b_hh = (const float*)d_in[4];
  const float* cg_w = (const float*)d_in[5];
  const float* cg_u = (const float*)d_in[6];
  const float* cg_b = (const float*)d_in[7];
  float* out = (float*)d_out;

  dim3 grid(GRID_), block(64);
  hipLaunchKernelGGL(cglstm_kernel, grid, block, 0, stream,
                     x, W_ih, W_hh, b_ih, b_hh, cg_w, cg_u, cg_b, out);
}

// Round 3
// 4123.616 us; speedup vs baseline: 19.9411x; 1.0276x over previous
//
#include <hip/hip_runtime.h>

// CGLSTMEncoder: 294912 independent sequences, T=120, H=32, D_IN=1.
// 32 threads per sequence, 2 sequences per wave (block=64=1 wave).
// Thread j owns gate element j; its weight rows live in arch VGPRs as
// float2-packed pairs so the 128 dot-FMAs/step issue as 64 v_pk_fma_f32.
// __launch_bounds__(64,2) budgets 256 regs/wave so the compiler does NOT
// stash weights in AGPRs (round-trips doubled issue in round 2: VGPR=84
// arch + ~100 AGPR at 4.2 ms). h is broadcast via LDS (same-address
// broadcast reads -> no bank pressure). Output gate `o` is dead code in
// the reference and skipped.

#define NV 9
#define TLEN 120
#define HS 32
#define BATCH_ 32768
#define NSEQ (BATCH_ * NV)   // 294912
#define NPAIR (NSEQ / 2)     // 147456
#define GRID_ 12288          // 12 pairs per block

typedef float vf2 __attribute__((ext_vector_type(2)));

__device__ __forceinline__ vf2 splat2(float x) { vf2 v; v.x = x; v.y = x; return v; }
__device__ __forceinline__ vf2 fma2(vf2 a, vf2 b, vf2 c) {
  return __builtin_elementwise_fma(a, b, c);
}

__device__ __forceinline__ float fast_exp2(float x) { return __builtin_amdgcn_exp2f(x); }
__device__ __forceinline__ float fast_rcp(float x)  { return __builtin_amdgcn_rcpf(x); }
// sigmoid(x) = 1/(1+2^(-x*log2e))
__device__ __forceinline__ float sigf(float x) {
  return fast_rcp(1.0f + fast_exp2(x * -1.44269504088896f));
}
// tanh(x) = sign(x)*(1 - 2/(2^(2|x|*log2e)+1)); NaN-safe for large |x|.
__device__ __forceinline__ float tanh_fast(float x) {
  float a = __builtin_fabsf(x);
  float e = fast_exp2(a * 2.88539008177793f);
  float r = fmaf(-2.0f, fast_rcp(1.0f + e), 1.0f);
  return __builtin_copysignf(r, x);
}

__global__ __launch_bounds__(64, 2) void cglstm_kernel(
    const float* __restrict__ x,      // [B, NV*TLEN]
    const float* __restrict__ W_ih,   // [128, 1] rows i,f,g,o
    const float* __restrict__ W_hh,   // [128, 32]
    const float* __restrict__ b_ih,   // [128]
    const float* __restrict__ b_hh,   // [128]
    const float* __restrict__ cg_w,   // [32, 1]
    const float* __restrict__ cg_u,   // [32, 32]
    const float* __restrict__ cg_b,   // [32]
    float* __restrict__ out)          // flat [s*HS + j]
{
  const int j   = threadIdx.x & 31;   // owned output element
  const int grp = threadIdx.x >> 5;   // which of the 2 sequences in this wave

  __shared__ float xs[2][TLEN];
  __shared__ float hb[2][HS];

  // ---- one-time weight load: float2-packed (i,f) and (g,cg) rows ----
  vf2 wif[HS], wgu[HS];
#pragma unroll
  for (int k = 0; k < HS; ++k) {
    vf2 a, b;
    a.x = W_hh[j * HS + k];            // i row
    a.y = W_hh[(HS + j) * HS + k];     // f row
    b.x = W_hh[(2 * HS + j) * HS + k]; // g row
    b.y = cg_u[j * HS + k];            // cg row
    wif[k] = a; wgu[k] = b;
  }
  vf2 wxif, wxgu, bif, bgu;
  wxif.x = W_ih[j];          wxif.y = W_ih[HS + j];
  wxgu.x = W_ih[2 * HS + j]; wxgu.y = cg_w[j];
  bif.x = b_ih[j] + b_hh[j];
  bif.y = b_ih[HS + j] + b_hh[HS + j];
  bgu.x = b_ih[2 * HS + j] + b_hh[2 * HS + j];
  bgu.y = cg_b[j];

  for (int p = blockIdx.x; p < NPAIR; p += GRID_) {
    const int s = p * 2 + grp;
    const int b = s / NV;
    const int v = s - b * NV;
    const float* xp = x + (size_t)b * (NV * TLEN) + (size_t)v * TLEN;

    // stage this sequence's 120 inputs into LDS
    xs[grp][j]      = xp[j];
    xs[grp][j + 32] = xp[j + 32];
    xs[grp][j + 64] = xp[j + 64];
    if (j < TLEN - 96) xs[grp][j + 96] = xp[j + 96];
    hb[grp][j] = 0.0f;
    float c = 0.0f, hn = 0.0f;
    __syncthreads();

#pragma unroll 1
    for (int t = 0; t < TLEN; ++t) {
      const float xt = xs[grp][t];
      // 4 independent pk chains: (i,f)x2, (g,cg)x2
      vf2 aif0 = fma2(wxif, splat2(xt), bif);
      vf2 agu0 = fma2(wxgu, splat2(xt), bgu);
      vf2 aif1 = splat2(0.0f);
      vf2 agu1 = splat2(0.0f);
      const float4* h4 = reinterpret_cast<const float4*>(&hb[grp][0]);
#pragma unroll
      for (int kb = 0; kb < 8; ++kb) {
        const float4 hv = h4[kb];
        aif0 = fma2(wif[4 * kb + 0], splat2(hv.x), aif0);
        agu0 = fma2(wgu[4 * kb + 0], splat2(hv.x), agu0);
        aif1 = fma2(wif[4 * kb + 1], splat2(hv.y), aif1);
        agu1 = fma2(wgu[4 * kb + 1], splat2(hv.y), agu1);
        aif0 = fma2(wif[4 * kb + 2], splat2(hv.z), aif0);
        agu0 = fma2(wgu[4 * kb + 2], splat2(hv.z), agu0);
        aif1 = fma2(wif[4 * kb + 3], splat2(hv.w), aif1);
        agu1 = fma2(wgu[4 * kb + 3], splat2(hv.w), agu1);
      }
      const vf2 aif = aif0 + aif1;
      const vf2 agu = agu0 + agu1;
      c  = fmaf(sigf(aif.y), c, sigf(aif.x) * tanh_fast(agu.x));
      hn = sigf(agu.y) * tanh_fast(c);
      __syncthreads();            // all lanes done reading h(t-1)
      hb[grp][j] = hn;
      __syncthreads();            // h(t) visible before next step's reads
    }

    out[(size_t)s * HS + j] = hn;  // coalesced across the wave
    __syncthreads();               // xs/hb safe to overwrite next pair
  }
}

extern "C" void kernel_launch(void* const* d_in, const int* in_sizes, int n_in,
                              void* d_out, int out_size, void* d_ws, size_t ws_size,
                              hipStream_t stream) {
  const float* x    = (const float*)d_in[0];
  const float* W_ih = (const float*)d_in[1];
  const float* W_hh = (const float*)d_in[2];
  const float* b_ih = (const float*)d_in[3];
  const float* b_hh = (const float*)d_in[4];
  const float* cg_w = (const float*)d_in[5];
  const float* cg_u = (const float*)d_in[6];
  const float* cg_b = (const float*)d_in[7];
  float* out = (float*)d_out;

  dim3 grid(GRID_), block(64);
  hipLaunchKernelGGL(cglstm_kernel, grid, block, 0, stream,
                     x, W_ih, W_hh, b_ih, b_hh, cg_w, cg_u, cg_b, out);
}

// Round 4
// 1621.542 us; speedup vs baseline: 50.7107x; 2.5430x over previous
//
#include <hip/hip_runtime.h>

// CGLSTMEncoder via MFMA: 294912 seqs, T=120, H=32, D_IN=1.
// 16 sequences per wave (block = 64 = 1 wave). Per step:
//   gates[16x128] = h[16x32] @ W^T  as 8 mfma_f32_16x16x32_bf16 tiles,
//   hi/lo bf16 split on BOTH operands (3 MFMAs/tile, lo*lo dropped) => ~fp32.
// c stays fp32 in registers (C/D layout). h round-trips through LDS packed
// as (bf16hi | bf16lo<<16) words; x is staged transposed in LDS.
// Gate order i,f,g,o: o is dead code in the reference and skipped; tiles
// 0,1=i 2,3=f 4,5=g 6,7=cg (cg_u rows).
// Layout set (verified m89/m91/m120): A: m=lane&15,k=quad*8+j; B: n=lane&15
// holds W rows over k; C/D: col=lane&15, row=quad*4+reg.

#define NV 9
#define TLEN 120
#define HS 32
#define BATCH_ 32768
#define NSEQ (BATCH_ * NV)
#define NBATCH (NSEQ / 16)   // 18432 batches of 16 seqs
#define GRID_ 6144           // 3 batches/block; exact rounds at 2 or 3 waves/SIMD

#define XSTRIDE 17           // words per t-row of xT (conflict-free 4-broadcast)
#define HSTRIDE 36           // words per seq-row of hbuf (16B-aligned, 2-way banks)

typedef __attribute__((ext_vector_type(8))) short bf16x8;
typedef __attribute__((ext_vector_type(4))) float f32x4;
typedef __attribute__((ext_vector_type(4))) unsigned int u32x4;

__device__ __forceinline__ float fast_exp2(float x) { return __builtin_amdgcn_exp2f(x); }
__device__ __forceinline__ float fast_rcp(float x)  { return __builtin_amdgcn_rcpf(x); }
__device__ __forceinline__ float sigf(float x) {
  return fast_rcp(1.0f + fast_exp2(x * -1.44269504088896f));
}
// tanh(x) = 2*sigma(2x)-1; NaN-safe at both infinities.
__device__ __forceinline__ float tanhf_(float x) {
  return fmaf(-2.0f, fast_rcp(1.0f + fast_exp2(x * -2.88539008177793f)), 1.0f);
}
__device__ __forceinline__ unsigned int fbits(float x) { return __builtin_bit_cast(unsigned int, x); }
__device__ __forceinline__ float bcastf(unsigned int x) { return __builtin_bit_cast(float, x); }

__global__ __launch_bounds__(64, 2) void cglstm_kernel(
    const float* __restrict__ x,      // [B, NV*TLEN]
    const float* __restrict__ W_ih,   // [128, 1]
    const float* __restrict__ W_hh,   // [128, 32]
    const float* __restrict__ b_ih,   // [128]
    const float* __restrict__ b_hh,   // [128]
    const float* __restrict__ cg_w,   // [32, 1]
    const float* __restrict__ cg_u,   // [32, 32]
    const float* __restrict__ cg_b,   // [32]
    float* __restrict__ out)          // flat [s*HS + j]
{
  const int lane = threadIdx.x;
  const int col  = lane & 15;
  const int quad = lane >> 4;

  __shared__ float xT[TLEN * XSTRIDE];
  __shared__ unsigned int hbuf[16 * HSTRIDE];

  // ---- one-time: B fragments (W rows) as bf16 hi/lo + per-column x-weights ----
  bf16x8 bhi[8], blo[8];
  float wx[8], bb[8];
#pragma unroll
  for (int tile = 0; tile < 8; ++tile) {
    const int n = col + (tile & 1) * 16;   // output column (gate element)
    const float* wrow = (tile < 6) ? (W_hh + (size_t)((tile >> 1) * HS + n) * HS)
                                   : (cg_u + (size_t)n * HS);
    bf16x8 vh, vl;
#pragma unroll
    for (int e = 0; e < 8; ++e) {
      float wv = wrow[quad * 8 + e];
      unsigned int wbits = fbits(wv);
      float lo_f = wv - bcastf(wbits & 0xffff0000u);
      vh[e] = (short)(wbits >> 16);
      vl[e] = (short)(fbits(lo_f) >> 16);
    }
    bhi[tile] = vh; blo[tile] = vl;
    if (tile < 6) {
      const int gg = tile >> 1;
      wx[tile] = W_ih[gg * HS + n];
      bb[tile] = b_ih[gg * HS + n] + b_hh[gg * HS + n];
    } else {
      wx[tile] = cg_w[n];
      bb[tile] = cg_b[n];
    }
  }

  for (int p = blockIdx.x; p < NBATCH; p += GRID_) {
    // ---- stage x^T (16 seqs contiguous: 1920 floats = 480 float4) ----
    const float4* xb = (const float4*)(x + (size_t)p * 16 * TLEN);
    for (int i = lane; i < 480; i += 64) {
      float4 v = xb[i];
      int f0 = i * 4;
      int s  = f0 / TLEN;
      int t0 = f0 - s * TLEN;          // multiple of 4, <= 116
      xT[(t0 + 0) * XSTRIDE + s] = v.x;
      xT[(t0 + 1) * XSTRIDE + s] = v.y;
      xT[(t0 + 2) * XSTRIDE + s] = v.z;
      xT[(t0 + 3) * XSTRIDE + s] = v.w;
    }
    for (int i = lane; i < 16 * HSTRIDE; i += 64) hbuf[i] = 0u;
    f32x4 c0 = {0.f, 0.f, 0.f, 0.f}, c1 = c0, h0 = c0, h1 = c0;
    __syncthreads();

#pragma unroll 1
    for (int t = 0; t < TLEN; ++t) {
      // x for this lane's 4 seqs (16-lane broadcast reads, conflict-free)
      float xt0 = xT[t * XSTRIDE + quad * 4 + 0];
      float xt1 = xT[t * XSTRIDE + quad * 4 + 1];
      float xt2 = xT[t * XSTRIDE + quad * 4 + 2];
      float xt3 = xT[t * XSTRIDE + quad * 4 + 3];
      // acc init = bias + wx * x  (C operand of first MFMA)
      f32x4 acc[8];
#pragma unroll
      for (int tile = 0; tile < 8; ++tile) {
        acc[tile][0] = fmaf(wx[tile], xt0, bb[tile]);
        acc[tile][1] = fmaf(wx[tile], xt1, bb[tile]);
        acc[tile][2] = fmaf(wx[tile], xt2, bb[tile]);
        acc[tile][3] = fmaf(wx[tile], xt3, bb[tile]);
      }
      // A fragments: h[m = col][k = quad*8 .. +7], hi/lo from packed words
      const unsigned int* hrow = &hbuf[col * HSTRIDE + quad * 8];
      u32x4 wa = *(const u32x4*)hrow;
      u32x4 wz = *(const u32x4*)(hrow + 4);
      u32x4 hi4, lo4;
      hi4[0] = __builtin_amdgcn_perm(wa[1], wa[0], 0x05040100u);
      hi4[1] = __builtin_amdgcn_perm(wa[3], wa[2], 0x05040100u);
      hi4[2] = __builtin_amdgcn_perm(wz[1], wz[0], 0x05040100u);
      hi4[3] = __builtin_amdgcn_perm(wz[3], wz[2], 0x05040100u);
      lo4[0] = __builtin_amdgcn_perm(wa[1], wa[0], 0x07060302u);
      lo4[1] = __builtin_amdgcn_perm(wa[3], wa[2], 0x07060302u);
      lo4[2] = __builtin_amdgcn_perm(wz[1], wz[0], 0x07060302u);
      lo4[3] = __builtin_amdgcn_perm(wz[3], wz[2], 0x07060302u);
      bf16x8 ahi = __builtin_bit_cast(bf16x8, hi4);
      bf16x8 alo = __builtin_bit_cast(bf16x8, lo4);
#pragma unroll
      for (int tile = 0; tile < 8; ++tile) {
        acc[tile] = __builtin_amdgcn_mfma_f32_16x16x32_bf16(ahi, bhi[tile], acc[tile], 0, 0, 0);
        acc[tile] = __builtin_amdgcn_mfma_f32_16x16x32_bf16(alo, bhi[tile], acc[tile], 0, 0, 0);
        acc[tile] = __builtin_amdgcn_mfma_f32_16x16x32_bf16(ahi, blo[tile], acc[tile], 0, 0, 0);
      }
      // elementwise: lane owns (seq = quad*4+r, j = col) and (.., j = col+16)
#pragma unroll
      for (int r = 0; r < 4; ++r) {
        float si = sigf(acc[0][r]);
        float sf = sigf(acc[2][r]);
        float tg = tanhf_(acc[4][r]);
        float sc = sigf(acc[6][r]);
        c0[r] = fmaf(sf, c0[r], si * tg);
        float hv = sc * tanhf_(c0[r]);
        h0[r] = hv;
        unsigned int hbits = fbits(hv);
        float lof = hv - bcastf(hbits & 0xffff0000u);
        hbuf[(quad * 4 + r) * HSTRIDE + col] =
            __builtin_amdgcn_perm(fbits(lof), hbits, 0x07060302u);

        float si1 = sigf(acc[1][r]);
        float sf1 = sigf(acc[3][r]);
        float tg1 = tanhf_(acc[5][r]);
        float sc1 = sigf(acc[7][r]);
        c1[r] = fmaf(sf1, c1[r], si1 * tg1);
        float hv1 = sc1 * tanhf_(c1[r]);
        h1[r] = hv1;
        unsigned int hbits1 = fbits(hv1);
        float lof1 = hv1 - bcastf(hbits1 & 0xffff0000u);
        hbuf[(quad * 4 + r) * HSTRIDE + col + 16] =
            __builtin_amdgcn_perm(fbits(lof1), hbits1, 0x07060302u);
      }
      __syncthreads();   // h(t) visible before next step's A-frag reads
    }

    // ---- epilogue: out[(p*16 + seq)*32 + j] ----
    float* ob = out + (size_t)p * 16 * HS;
#pragma unroll
    for (int r = 0; r < 4; ++r) {
      ob[(quad * 4 + r) * HS + col]      = h0[r];
      ob[(quad * 4 + r) * HS + col + 16] = h1[r];
    }
    __syncthreads();   // xT/hbuf safe to restage
  }
}

extern "C" void kernel_launch(void* const* d_in, const int* in_sizes, int n_in,
                              void* d_out, int out_size, void* d_ws, size_t ws_size,
                              hipStream_t stream) {
  const float* x    = (const float*)d_in[0];
  const float* W_ih = (const float*)d_in[1];
  const float* W_hh = (const float*)d_in[2];
  const float* b_ih = (const float*)d_in[3];
  const float* b_hh = (const float*)d_in[4];
  const float* cg_w = (const float*)d_in[5];
  const float* cg_u = (const float*)d_in[6];
  const float* cg_b = (const float*)d_in[7];
  float* out = (float*)d_out;

  dim3 grid(GRID_), block(64);
  hipLaunchKernelGGL(cglstm_kernel, grid, block, 0, stream,
                     x, W_ih, W_hh, b_ih, b_hh, cg_w, cg_u, cg_b, out);
}

// Round 5
// 1392.885 us; speedup vs baseline: 59.0354x; 1.1642x over previous
//
#include <hip/hip_runtime.h>

// CGLSTMEncoder via MFMA: 294912 seqs, T=120, H=32, D_IN=1.
// 16 seqs/wave, 8 mfma_f32_16x16x32_bf16 tiles/step (hi/lo bf16 split, 3
// MFMAs/tile => ~fp32). Round-5 change: transcendental-minimal elementwise.
//   * Weights/biases prescaled by -log2e (g gate: -2log2e) so every exp2
//     argument comes straight out of the accumulator (no argument muls).
//   * Cell state kept scaled: ct = -2*log2e*c.
//   * All 5 reciprocals merged into 2:
//       ct' = [ct*(1+Ei)(1+Eg) + (1+Ef)*fma(Eg,2L,-2L)] * rcp[(1+Ef)(1+Ei)(1+Eg)]
//       h   = (1-Ec) * rcp[(1+Ea)(1+Ec)]
//     (exact algebra: sigmoid/tanh in e^-x form; 7 trans/element vs 10.)
//   * Full-rate math on f32x4 so clang can emit v_pk_*_f32.
// Gate order i,f,g,o: o is dead code in the reference and skipped.
// Layouts (verified): A: m=lane&15,k=quad*8+j; B: n=lane&15 holds W rows;
// C/D: col=lane&15, row=quad*4+reg.

#define NV 9
#define TLEN 120
#define HS 32
#define BATCH_ 32768
#define NSEQ (BATCH_ * NV)
#define NBATCH (NSEQ / 16)   // 18432 batches of 16 seqs
#define GRID_ 6144           // 3 batches/block

#define XSTRIDE 20           // words per t-row of xT (16B-aligned quad reads)
#define HSTRIDE 36           // words per seq-row of hbuf

#define LOG2E 1.4426950408889634f
#define TWOL  2.8853900817779268f

typedef __attribute__((ext_vector_type(8))) short bf16x8;
typedef __attribute__((ext_vector_type(4))) float f32x4;
typedef __attribute__((ext_vector_type(4))) unsigned int u32x4;

__device__ __forceinline__ float fast_exp2(float x) { return __builtin_amdgcn_exp2f(x); }
__device__ __forceinline__ float fast_rcp(float x)  { return __builtin_amdgcn_rcpf(x); }
__device__ __forceinline__ unsigned int fbits(float x) { return __builtin_bit_cast(unsigned int, x); }
__device__ __forceinline__ float bcastf(unsigned int x) { return __builtin_bit_cast(float, x); }

__device__ __forceinline__ f32x4 splat4(float x) { f32x4 v = {x, x, x, x}; return v; }
__device__ __forceinline__ f32x4 fma4(f32x4 a, f32x4 b, f32x4 c) {
  return __builtin_elementwise_fma(a, b, c);
}
__device__ __forceinline__ f32x4 exp24(f32x4 v) {
  f32x4 r;
  r[0] = fast_exp2(v[0]); r[1] = fast_exp2(v[1]);
  r[2] = fast_exp2(v[2]); r[3] = fast_exp2(v[3]);
  return r;
}
__device__ __forceinline__ f32x4 rcp4(f32x4 v) {
  f32x4 r;
  r[0] = fast_rcp(v[0]); r[1] = fast_rcp(v[1]);
  r[2] = fast_rcp(v[2]); r[3] = fast_rcp(v[3]);
  return r;
}

// merged-LSTM elementwise for 4 seqs: inputs are PRESCALED pre-activations
// (ai,af,ac by -log2e; ag by -2log2e); ct is the scaled cell state.
__device__ __forceinline__ void lstm_elem(f32x4 ai, f32x4 af, f32x4 ag, f32x4 ac,
                                          f32x4& ct, f32x4& h) {
  const f32x4 one4 = splat4(1.0f);
  f32x4 Ei = exp24(ai), Ef = exp24(af), Eg = exp24(ag), Ea = exp24(ac);
  f32x4 pi_ = Ei + one4, pf_ = Ef + one4, pg_ = Eg + one4, pa_ = Ea + one4;
  f32x4 u   = fma4(Eg, splat4(TWOL), splat4(-TWOL));   // (-2L)*(1-Eg)
  f32x4 P   = pi_ * pg_;
  f32x4 tt  = pf_ * u;
  f32x4 num = fma4(ct, P, tt);
  f32x4 den = pf_ * P;
  ct = num * rcp4(den);
  f32x4 Ec  = exp24(ct);
  h = (one4 - Ec) * rcp4(pa_ * (Ec + one4));
}

__global__ __launch_bounds__(64, 2) void cglstm_kernel(
    const float* __restrict__ x,      // [B, NV*TLEN]
    const float* __restrict__ W_ih,   // [128, 1]
    const float* __restrict__ W_hh,   // [128, 32]
    const float* __restrict__ b_ih,   // [128]
    const float* __restrict__ b_hh,   // [128]
    const float* __restrict__ cg_w,   // [32, 1]
    const float* __restrict__ cg_u,   // [32, 32]
    const float* __restrict__ cg_b,   // [32]
    float* __restrict__ out)          // flat [s*HS + j]
{
  const int lane = threadIdx.x;
  const int col  = lane & 15;
  const int quad = lane >> 4;

  __shared__ __align__(16) float xT[TLEN * XSTRIDE];
  __shared__ unsigned int hbuf[16 * HSTRIDE];

  // ---- one-time: prescaled B fragments (W rows) as bf16 hi/lo ----
  bf16x8 bhi[8], blo[8];
  float wx[8], bb[8];
#pragma unroll
  for (int tile = 0; tile < 8; ++tile) {
    const int n = col + (tile & 1) * 16;
    const float sc_ = ((tile >> 1) == 2) ? -TWOL : -LOG2E;  // g gate: -2L
    const float* wrow = (tile < 6) ? (W_hh + (size_t)((tile >> 1) * HS + n) * HS)
                                   : (cg_u + (size_t)n * HS);
    bf16x8 vh, vl;
#pragma unroll
    for (int e = 0; e < 8; ++e) {
      float wv = wrow[quad * 8 + e] * sc_;
      unsigned int wbits = fbits(wv);
      float lo_f = wv - bcastf(wbits & 0xffff0000u);
      vh[e] = (short)(wbits >> 16);
      vl[e] = (short)(fbits(lo_f) >> 16);
    }
    bhi[tile] = vh; blo[tile] = vl;
    if (tile < 6) {
      const int gg = tile >> 1;
      wx[tile] = W_ih[gg * HS + n] * sc_;
      bb[tile] = (b_ih[gg * HS + n] + b_hh[gg * HS + n]) * sc_;
    } else {
      wx[tile] = cg_w[n] * sc_;
      bb[tile] = cg_b[n] * sc_;
    }
  }

  for (int p = blockIdx.x; p < NBATCH; p += GRID_) {
    // ---- stage x^T (16 seqs contiguous: 1920 floats = 480 float4) ----
    const float4* xb = (const float4*)(x + (size_t)p * 16 * TLEN);
    for (int i = lane; i < 480; i += 64) {
      float4 v = xb[i];
      int f0 = i * 4;
      int s  = f0 / TLEN;
      int t0 = f0 - s * TLEN;
      xT[(t0 + 0) * XSTRIDE + s] = v.x;
      xT[(t0 + 1) * XSTRIDE + s] = v.y;
      xT[(t0 + 2) * XSTRIDE + s] = v.z;
      xT[(t0 + 3) * XSTRIDE + s] = v.w;
    }
    for (int i = lane; i < 16 * HSTRIDE; i += 64) hbuf[i] = 0u;
    f32x4 ct0 = splat4(0.f), ct1 = splat4(0.f), h0 = splat4(0.f), h1 = splat4(0.f);
    __syncthreads();

#pragma unroll 1
    for (int t = 0; t < TLEN; ++t) {
      // x for this lane's 4 seqs: one 16B broadcast read
      f32x4 xt4 = *(const f32x4*)&xT[t * XSTRIDE + quad * 4];
      f32x4 acc[8];
#pragma unroll
      for (int tile = 0; tile < 8; ++tile)
        acc[tile] = fma4(splat4(wx[tile]), xt4, splat4(bb[tile]));
      // A fragments: h[m=col][k=quad*8..+7], hi/lo from packed words
      const unsigned int* hrow = &hbuf[col * HSTRIDE + quad * 8];
      u32x4 wa = *(const u32x4*)hrow;
      u32x4 wz = *(const u32x4*)(hrow + 4);
      u32x4 hi4, lo4;
      hi4[0] = __builtin_amdgcn_perm(wa[1], wa[0], 0x05040100u);
      hi4[1] = __builtin_amdgcn_perm(wa[3], wa[2], 0x05040100u);
      hi4[2] = __builtin_amdgcn_perm(wz[1], wz[0], 0x05040100u);
      hi4[3] = __builtin_amdgcn_perm(wz[3], wz[2], 0x05040100u);
      lo4[0] = __builtin_amdgcn_perm(wa[1], wa[0], 0x07060302u);
      lo4[1] = __builtin_amdgcn_perm(wa[3], wa[2], 0x07060302u);
      lo4[2] = __builtin_amdgcn_perm(wz[1], wz[0], 0x07060302u);
      lo4[3] = __builtin_amdgcn_perm(wz[3], wz[2], 0x07060302u);
      bf16x8 ahi = __builtin_bit_cast(bf16x8, hi4);
      bf16x8 alo = __builtin_bit_cast(bf16x8, lo4);
#pragma unroll
      for (int tile = 0; tile < 8; ++tile) {
        acc[tile] = __builtin_amdgcn_mfma_f32_16x16x32_bf16(ahi, bhi[tile], acc[tile], 0, 0, 0);
        acc[tile] = __builtin_amdgcn_mfma_f32_16x16x32_bf16(alo, bhi[tile], acc[tile], 0, 0, 0);
        acc[tile] = __builtin_amdgcn_mfma_f32_16x16x32_bf16(ahi, blo[tile], acc[tile], 0, 0, 0);
      }
      // merged elementwise (7 trans/element), halves j=col and j=col+16
      lstm_elem(acc[0], acc[2], acc[4], acc[6], ct0, h0);
      lstm_elem(acc[1], acc[3], acc[5], acc[7], ct1, h1);
      // pack h -> (bf16hi | bf16lo) words for next step's A fragments
#pragma unroll
      for (int r = 0; r < 4; ++r) {
        unsigned int hbits = fbits(h0[r]);
        float lof = h0[r] - bcastf(hbits & 0xffff0000u);
        hbuf[(quad * 4 + r) * HSTRIDE + col] =
            __builtin_amdgcn_perm(fbits(lof), hbits, 0x07060302u);
        unsigned int hbits1 = fbits(h1[r]);
        float lof1 = h1[r] - bcastf(hbits1 & 0xffff0000u);
        hbuf[(quad * 4 + r) * HSTRIDE + col + 16] =
            __builtin_amdgcn_perm(fbits(lof1), hbits1, 0x07060302u);
      }
      __syncthreads();   // h(t) visible before next step's A-frag reads
    }

    // ---- epilogue ----
    float* ob = out + (size_t)p * 16 * HS;
#pragma unroll
    for (int r = 0; r < 4; ++r) {
      ob[(quad * 4 + r) * HS + col]      = h0[r];
      ob[(quad * 4 + r) * HS + col + 16] = h1[r];
    }
    __syncthreads();   // xT/hbuf safe to restage
  }
}

extern "C" void kernel_launch(void* const* d_in, const int* in_sizes, int n_in,
                              void* d_out, int out_size, void* d_ws, size_t ws_size,
                              hipStream_t stream) {
  const float* x    = (const float*)d_in[0];
  const float* W_ih = (const float*)d_in[1];
  const float* W_hh = (const float*)d_in[2];
  const float* b_ih = (const float*)d_in[3];
  const float* b_hh = (const float*)d_in[4];
  const float* cg_w = (const float*)d_in[5];
  const float* cg_u = (const float*)d_in[6];
  const float* cg_b = (const float*)d_in[7];
  float* out = (float*)d_out;

  dim3 grid(GRID_), block(64);
  hipLaunchKernelGGL(cglstm_kernel, grid, block, 0, stream,
                     x, W_ih, W_hh, b_ih, b_hh, cg_w, cg_u, cg_b, out);
}